// Round 5
// baseline (58265.186 us; speedup 1.0000x reference)
//
#include <hip/hip_runtime.h>
#include <math.h>

#define DMODEL 768
#define HN 12
#define DHEAD 64
#define DFF 3072
#define VOC 30522
#define BB 8
#define SS 128
#define KW 4
#define TT 32
#define CHN 239   // ceil(30522/128)
#define P32 (32 * DMODEL)
#define NBLK 256

__device__ __forceinline__ float gelu_f(float x) {
    float x3 = x * x * x;
    return 0.5f * x * (1.0f + tanhf(0.7978845608028654f * (x + 0.044715f * x3)));
}

// ---- device-scope grid barrier (persistent-kernel pattern) ----
// bar[0] = arrive count, bar[1] = generation. Zeroed by init_k each launch.
__device__ __forceinline__ void grid_bar(int* bar, int& gen_local) {
    __syncthreads();
    if (threadIdx.x == 0) {
        int target = ++gen_local;
        int ticket = __hip_atomic_fetch_add(&bar[0], 1, __ATOMIC_ACQ_REL,
                                            __HIP_MEMORY_SCOPE_AGENT);
        if (ticket == NBLK - 1) {
            __hip_atomic_store(&bar[0], 0, __ATOMIC_RELAXED, __HIP_MEMORY_SCOPE_AGENT);
            __hip_atomic_store(&bar[1], target, __ATOMIC_RELEASE, __HIP_MEMORY_SCOPE_AGENT);
        } else {
            while (__hip_atomic_load(&bar[1], __ATOMIC_ACQUIRE,
                                     __HIP_MEMORY_SCOPE_AGENT) < target) {
                __builtin_amdgcn_s_sleep(2);
            }
        }
    }
    __syncthreads();
}

// ---- init tokens/scores + barrier state ----
__global__ void init_k(int* tokens, float* scores, int* bar) {
    int i = threadIdx.x;
    if (i < BB * KW) {
        tokens[i] = 101;                      // BOS
        scores[i] = (i & 3) ? -1e9f : 0.0f;
    }
    if (i < 2) bar[i] = 0;
}

// ============================ ENCODER (separate kernels) ============================

__global__ __launch_bounds__(256) void embed_enc(const int* __restrict__ X,
                                                 const float* __restrict__ emb,
                                                 const float* __restrict__ pos,
                                                 float* __restrict__ h,
                                                 float* __restrict__ mb) {
    int row = blockIdx.x;
    int s = row & (SS - 1);
    int tok = X[row];
    const float* e = emb + (size_t)tok * DMODEL;
    const float* p = pos + (size_t)s * DMODEL;
    float* hp = h + (size_t)row * DMODEL;
    for (int c = threadIdx.x; c < DMODEL; c += 256) hp[c] = e[c] + p[c];
    if (threadIdx.x == 0) mb[row] = (tok != 0) ? 0.0f : -1e9f;
}

template<int KD, int ACT>
__global__ __launch_bounds__(256) void gemm64(const float* __restrict__ A,
                                              const float* __restrict__ B,
                                              float* __restrict__ C, int N) {
    __shared__ float As[16][68];
    __shared__ float Bs[16][68];
    int tid = threadIdx.x;
    int tx = tid & 15, ty = tid >> 4;
    int bm = blockIdx.y * 64, bn = blockIdx.x * 64;
    int a_gk = tid & 15, a_gm0 = tid >> 4;
    int b_gn = tid & 63, b_gk0 = tid >> 6;
    float ra[4], rb[4];
    float acc[4][4] = {};
#pragma unroll
    for (int p = 0; p < 4; p++) ra[p] = A[(size_t)(bm + a_gm0 + p * 16) * KD + a_gk];
#pragma unroll
    for (int p = 0; p < 4; p++) rb[p] = B[(size_t)(b_gk0 + p * 4) * N + bn + b_gn];
    for (int k0 = 0; k0 < KD; k0 += 16) {
        __syncthreads();
#pragma unroll
        for (int p = 0; p < 4; p++) As[a_gk][a_gm0 + p * 16] = ra[p];
#pragma unroll
        for (int p = 0; p < 4; p++) Bs[b_gk0 + p * 4][b_gn] = rb[p];
        __syncthreads();
        if (k0 + 16 < KD) {
#pragma unroll
            for (int p = 0; p < 4; p++) ra[p] = A[(size_t)(bm + a_gm0 + p * 16) * KD + k0 + 16 + a_gk];
#pragma unroll
            for (int p = 0; p < 4; p++) rb[p] = B[(size_t)(k0 + 16 + b_gk0 + p * 4) * N + bn + b_gn];
        }
#pragma unroll
        for (int kk = 0; kk < 16; kk++) {
            float4 a4 = *(const float4*)&As[kk][ty * 4];
            float4 b4 = *(const float4*)&Bs[kk][tx * 4];
            float av[4] = {a4.x, a4.y, a4.z, a4.w};
            float bv[4] = {b4.x, b4.y, b4.z, b4.w};
#pragma unroll
            for (int i = 0; i < 4; i++)
#pragma unroll
                for (int j = 0; j < 4; j++) acc[i][j] += av[i] * bv[j];
        }
    }
#pragma unroll
    for (int i = 0; i < 4; i++)
#pragma unroll
        for (int j = 0; j < 4; j++) {
            float v = acc[i][j];
            if (ACT) v = gelu_f(v);
            C[(size_t)(bm + ty * 4 + i) * N + bn + tx * 4 + j] = v;
        }
}

__global__ __launch_bounds__(64) void enc_attn(const float* __restrict__ q,
                                               const float* __restrict__ k,
                                               const float* __restrict__ v,
                                               const float* __restrict__ mb,
                                               float* __restrict__ ctx) {
    int bid = blockIdx.x;
    int qi = bid & (SS - 1);
    int h = (bid >> 7) % HN;
    int b = bid / (SS * HN);
    int lane = threadIdx.x;
    __shared__ float qs[DHEAD];
    __shared__ float att[SS];
    qs[lane] = q[((size_t)(b * SS + qi) * HN + h) * DHEAD + lane];
    __syncthreads();
    const float* kb = k + ((size_t)(b * SS) * HN + h) * DHEAD;
    const float* k0p = kb + (size_t)lane * DMODEL;
    const float* k1p = kb + (size_t)(lane + 64) * DMODEL;
    float s0 = 0.f, s1 = 0.f;
#pragma unroll 8
    for (int d = 0; d < DHEAD; d++) {
        float qd = qs[d];
        s0 += qd * k0p[d];
        s1 += qd * k1p[d];
    }
    s0 = s0 * 0.125f + mb[b * SS + lane];
    s1 = s1 * 0.125f + mb[b * SS + lane + 64];
    float m = fmaxf(s0, s1);
    for (int off = 32; off; off >>= 1) m = fmaxf(m, __shfl_xor(m, off, 64));
    float e0 = expf(s0 - m), e1 = expf(s1 - m);
    float sum = e0 + e1;
    for (int off = 32; off; off >>= 1) sum += __shfl_xor(sum, off, 64);
    float inv = 1.0f / sum;
    att[lane] = e0 * inv;
    att[lane + 64] = e1 * inv;
    __syncthreads();
    const float* vb = v + ((size_t)(b * SS) * HN + h) * DHEAD + lane;
    float acc = 0.f;
#pragma unroll 8
    for (int key = 0; key < SS; key++) acc += att[key] * vb[(size_t)key * DMODEL];
    ctx[(size_t)(b * SS + qi) * DMODEL + h * DHEAD + lane] = acc;
}

__global__ __launch_bounds__(256) void lnres_enc(const float* __restrict__ A,
                                                 const float* __restrict__ Bsrc,
                                                 float* __restrict__ out) {
    int row = blockIdx.x, tid = threadIdx.x;
    const float* ap = A + (size_t)row * DMODEL;
    const float* bp = Bsrc + (size_t)row * DMODEL;
    float x[3];
#pragma unroll
    for (int i = 0; i < 3; i++) x[i] = ap[tid + 256 * i] + bp[tid + 256 * i];
    __shared__ float red[256];
    red[tid] = x[0] + x[1] + x[2];
    __syncthreads();
    for (int off = 128; off; off >>= 1) { if (tid < off) red[tid] += red[tid + off]; __syncthreads(); }
    float mean = red[0] * (1.0f / DMODEL);
    __syncthreads();
    float d[3], s2 = 0.f;
#pragma unroll
    for (int i = 0; i < 3; i++) { d[i] = x[i] - mean; s2 += d[i] * d[i]; }
    red[tid] = s2;
    __syncthreads();
    for (int off = 128; off; off >>= 1) { if (tid < off) red[tid] += red[tid + off]; __syncthreads(); }
    float inv = 1.0f / sqrtf(red[0] * (1.0f / DMODEL) + 1e-5f);
    float* op = out + (size_t)row * DMODEL;
#pragma unroll
    for (int i = 0; i < 3; i++) op[tid + 256 * i] = d[i] * inv;
}

// ============================ DECODER MEGAKERNEL ============================

template<int KRANGE, int APL, int AGELU, int TOUT, int GATHER>
__device__ __forceinline__ void dev_skinny(float* Als, const float* At, const float* B,
                                           float* C, int N, int aPlaneF4, int bx, int by,
                                           const int* tokens, const float* emb,
                                           const float* pos, int t) {
    constexpr int SK = (KRANGE > 192) ? 192 : KRANGE;
    constexpr int NST = KRANGE / SK;
    int tid = threadIdx.x;
    int lane = tid & 63, q = tid >> 6;
    int col0 = bx * 128 + lane * 2;
    float acc[8][2] = {};
    for (int st = 0; st < NST; st++) {
        int kbase = by * KRANGE + st * SK;
        __syncthreads();
        if constexpr (GATHER) {
            int r = tid & 31;
            int tok = tokens[r];
            const float* er = emb + (size_t)tok * DMODEL;
            const float* pr = pos + (size_t)t * DMODEL;
            for (int kk = tid >> 5; kk < SK; kk += 8) {
                int k = kbase + kk;
                Als[kk * 32 + r] = er[k] + pr[k];
            }
        } else {
            const float4* srcb = ((const float4*)At) + (size_t)kbase * 8;
            float4* dst = (float4*)Als;
#pragma unroll
            for (int i = 0; i < SK / 32; i++) {
                float4 v = srcb[i * 256 + tid];
#pragma unroll
                for (int p = 1; p < APL; p++) {
                    float4 w = srcb[(size_t)p * aPlaneF4 + i * 256 + tid];
                    v.x += w.x; v.y += w.y; v.z += w.z; v.w += w.w;
                }
                if (AGELU) { v.x = gelu_f(v.x); v.y = gelu_f(v.y); v.z = gelu_f(v.z); v.w = gelu_f(v.w); }
                dst[i * 256 + tid] = v;
            }
        }
        __syncthreads();
        const float* Bp = B + (size_t)kbase * N + col0;
#pragma unroll 8
        for (int k = 0; k < SK; k++) {
            float2 bv = *(const float2*)(Bp + (size_t)k * N);
            float4 a0 = *(const float4*)&Als[k * 32 + q * 8];
            float4 a1 = *(const float4*)&Als[k * 32 + q * 8 + 4];
            float ar[8] = {a0.x, a0.y, a0.z, a0.w, a1.x, a1.y, a1.z, a1.w};
#pragma unroll
            for (int r = 0; r < 8; r++) {
                acc[r][0] += ar[r] * bv.x;
                acc[r][1] += ar[r] * bv.y;
            }
        }
    }
    float* Cb = C + (size_t)by * 32 * N;
    if (TOUT) {
#pragma unroll
        for (int c = 0; c < 2; c++) {
            float4 lo = {acc[0][c], acc[1][c], acc[2][c], acc[3][c]};
            float4 hi = {acc[4][c], acc[5][c], acc[6][c], acc[7][c]};
            *(float4*)&Cb[(size_t)(col0 + c) * 32 + q * 8] = lo;
            *(float4*)&Cb[(size_t)(col0 + c) * 32 + q * 8 + 4] = hi;
        }
    } else {
#pragma unroll
        for (int r = 0; r < 8; r++) {
            float2 st2 = {acc[r][0], acc[r][1]};
            *(float2*)&Cb[(size_t)(q * 8 + r) * N + col0] = st2;
        }
    }
}

__device__ __forceinline__ void dev_xwrite(int row, const int* tokens, const float* emb,
                                           const float* pos, int t, float* x) {
    int tok = tokens[row];
    const float* e = emb + (size_t)tok * DMODEL;
    const float* p = pos + (size_t)t * DMODEL;
    float* xp = x + (size_t)row * DMODEL;
    for (int c = threadIdx.x; c < DMODEL; c += 256) xp[c] = e[c] + p[c];
}

__device__ __forceinline__ void dev_attn(float* smem, int blk, const float* qdp,
                                         const float* Kmem, const float* Vmem,
                                         const float* mb, float* cctxT) {
    int tid = threadIdx.x;
    int lane = tid & 63, w = tid >> 6;
    int u = blk * 4 + w;
    int h = u % HN;
    int kb = (u / HN) & 3;
    int b = u / (HN * KW);
    int rowq = b * KW + kb;
    float* qs = smem + w * 192;
    float* att = qs + 64;
    const int QP = P32;
    size_t qoff = (size_t)rowq * DMODEL + h * DHEAD + lane;
    float qv = 0.f;
#pragma unroll
    for (int p = 0; p < 8; p++) qv += qdp[(size_t)p * QP + qoff];
    qs[lane] = qv;
    __syncthreads();
    const float* kb0 = Kmem + ((size_t)(b * SS) * HN + h) * DHEAD;
    const float* k0p = kb0 + (size_t)lane * DMODEL;
    const float* k1p = kb0 + (size_t)(lane + 64) * DMODEL;
    float s0 = 0.f, s1 = 0.f;
#pragma unroll 8
    for (int d = 0; d < DHEAD; d++) {
        float qd = qs[d];
        s0 += qd * k0p[d];
        s1 += qd * k1p[d];
    }
    s0 = s0 * 0.125f + mb[b * SS + lane];
    s1 = s1 * 0.125f + mb[b * SS + lane + 64];
    float m = fmaxf(s0, s1);
#pragma unroll
    for (int off = 32; off; off >>= 1) m = fmaxf(m, __shfl_xor(m, off, 64));
    float e0 = expf(s0 - m), e1 = expf(s1 - m);
    float sum = e0 + e1;
#pragma unroll
    for (int off = 32; off; off >>= 1) sum += __shfl_xor(sum, off, 64);
    float inv = 1.0f / sum;
    att[lane] = e0 * inv;
    att[lane + 64] = e1 * inv;
    __syncthreads();
    const float* vb = Vmem + ((size_t)(b * SS) * HN + h) * DHEAD + lane;
    float acc = 0.f;
#pragma unroll 8
    for (int key = 0; key < SS; key++) acc += att[key] * vb[(size_t)key * DMODEL];
    cctxT[(size_t)(h * DHEAD + lane) * 32 + rowq] = acc;
}

template<int P>
__device__ __forceinline__ void dev_lnres(float* red, int row, const float* A,
                                          const float* Bsrc, float* out, float* outT) {
    int tid = threadIdx.x;
    const float* ap = A + (size_t)row * DMODEL;
    float xv[3];
#pragma unroll
    for (int i = 0; i < 3; i++) {
        int idx = tid + 256 * i;
        float s = ap[idx];
#pragma unroll
        for (int p = 0; p < P; p++) s += Bsrc[(size_t)p * P32 + (size_t)row * DMODEL + idx];
        xv[i] = s;
    }
    red[tid] = xv[0] + xv[1] + xv[2];
    __syncthreads();
    for (int off = 128; off; off >>= 1) { if (tid < off) red[tid] += red[tid + off]; __syncthreads(); }
    float mean = red[0] * (1.0f / DMODEL);
    __syncthreads();
    float d0 = xv[0] - mean, d1 = xv[1] - mean, d2 = xv[2] - mean;
    red[tid] = d0 * d0 + d1 * d1 + d2 * d2;
    __syncthreads();
    for (int off = 128; off; off >>= 1) { if (tid < off) red[tid] += red[tid + off]; __syncthreads(); }
    float inv = 1.0f / sqrtf(red[0] * (1.0f / DMODEL) + 1e-5f);
    float v0 = d0 * inv, v1 = d1 * inv, v2 = d2 * inv;
    float* op = out + (size_t)row * DMODEL;
    op[tid] = v0; op[tid + 256] = v1; op[tid + 512] = v2;
    outT[(size_t)tid * 32 + row] = v0;
    outT[(size_t)(tid + 256) * 32 + row] = v1;
    outT[(size_t)(tid + 512) * 32 + row] = v2;
}

__device__ __forceinline__ void dev_logits(float* Als, int blk, const float* At,
                                           const float* B, float* cmax, float* csum,
                                           float* ctv, int* cti) {
    int tid = threadIdx.x;
    int lane = tid & 63, q = tid >> 6;
    int col0 = blk * 128 + lane * 2;
    bool valid = col0 < VOC;
    int jc = valid ? col0 : VOC - 2;
    float acc[8][2] = {};
    for (int st = 0; st < 4; st++) {
        int kbase = st * 192;
        __syncthreads();
        const float4* srcb = ((const float4*)At) + (size_t)kbase * 8;
        float4* dst = (float4*)Als;
#pragma unroll
        for (int i = 0; i < 6; i++) dst[i * 256 + tid] = srcb[i * 256 + tid];
        __syncthreads();
        const float* Bp = B + (size_t)kbase * VOC + jc;
#pragma unroll 8
        for (int k = 0; k < 192; k++) {
            float2 bv = *(const float2*)(Bp + (size_t)k * VOC);
            float4 a0 = *(const float4*)&Als[k * 32 + q * 8];
            float4 a1 = *(const float4*)&Als[k * 32 + q * 8 + 4];
            float ar[8] = {a0.x, a0.y, a0.z, a0.w, a1.x, a1.y, a1.z, a1.w};
#pragma unroll
            for (int r = 0; r < 8; r++) {
                acc[r][0] += ar[r] * bv.x;
                acc[r][1] += ar[r] * bv.y;
            }
        }
    }
#pragma unroll 1
    for (int r = 0; r < 8; r++) {
        float v0 = valid ? acc[r][0] : -INFINITY;
        float v1 = valid ? acc[r][1] : -INFINITY;
        float mx = fmaxf(v0, v1);
#pragma unroll
        for (int off = 32; off; off >>= 1) mx = fmaxf(mx, __shfl_xor(mx, off, 64));
        float ss = valid ? (expf(v0 - mx) + expf(v1 - mx)) : 0.0f;
#pragma unroll
        for (int off = 32; off; off >>= 1) ss += __shfl_xor(ss, off, 64);
        float c0 = v0, c1 = v1;
        int i0 = col0, i1 = col0 + 1;
        float tv[4]; int ti[4];
#pragma unroll
        for (int p = 0; p < 4; p++) {
            float bv; int bi;
            if (c0 > c1 || (c0 == c1 && i0 < i1)) { bv = c0; bi = i0; } else { bv = c1; bi = i1; }
#pragma unroll
            for (int off = 32; off; off >>= 1) {
                float ov = __shfl_xor(bv, off, 64);
                int oi = __shfl_xor(bi, off, 64);
                if (ov > bv || (ov == bv && oi < bi)) { bv = ov; bi = oi; }
            }
            if (bi == i0) c0 = -INFINITY;
            else if (bi == i1) c1 = -INFINITY;
            tv[p] = bv; ti[p] = bi;
        }
        if (lane == 0) {
            int m = q * 8 + r;
            int o = m * CHN + blk;
            cmax[o] = mx; csum[o] = ss;
            ctv[o * 4 + 0] = tv[0]; cti[o * 4 + 0] = ti[0];
            ctv[o * 4 + 1] = tv[1]; cti[o * 4 + 1] = ti[1];
            ctv[o * 4 + 2] = tv[2]; cti[o * 4 + 2] = ti[2];
            ctv[o * 4 + 3] = tv[3]; cti[o * 4 + 3] = ti[3];
        }
    }
}

__device__ __forceinline__ void dev_merge(float* smem, int b, const float* cmax,
                                          const float* csum, const float* ctv,
                                          const int* cti, float* scores, int* tokens,
                                          int* beamh, int* tokh, int t) {
    int tid = threadIdx.x;
    int lane = tid & 63, q = tid >> 6;
    int m = b * 4 + q;
    float* LSE = smem;
    float* s_old = smem + 4;
    float* bt_v = smem + 8;         // [4][4]
    int* bt_i = (int*)(smem + 24);  // [4][4]
    if (tid < 4) s_old[tid] = scores[b * 4 + tid];
    float mx = -INFINITY, sm = 0.f;
    for (int c = lane; c < CHN; c += 64) {
        float cm = cmax[m * CHN + c], cs = csum[m * CHN + c];
        if (cm > mx) { sm = sm * expf(mx - cm) + cs; mx = cm; }
        else sm += cs * expf(cm - mx);
    }
#pragma unroll
    for (int off = 32; off; off >>= 1) {
        float om = __shfl_xor(mx, off, 64);
        float os = __shfl_xor(sm, off, 64);
        float M = fmaxf(mx, om);
        sm = sm * expf(mx - M) + os * expf(om - M);
        mx = M;
    }
    if (lane == 0) LSE[q] = mx + logf(sm);
    float lv[4] = {-INFINITY, -INFINITY, -INFINITY, -INFINITY};
    int li[4] = {0x7fffffff, 0x7fffffff, 0x7fffffff, 0x7fffffff};
    for (int c = lane; c < CHN; c += 64) {
        int o = (m * CHN + c) * 4;
#pragma unroll
        for (int j = 0; j < 4; j++) {
            float v = ctv[o + j]; int i = cti[o + j];
            if (v > lv[3] || (v == lv[3] && i < li[3])) {
                lv[3] = v; li[3] = i;
#pragma unroll
                for (int s = 3; s > 0; s--) {
                    if (lv[s] > lv[s - 1] || (lv[s] == lv[s - 1] && li[s] < li[s - 1])) {
                        float tv2 = lv[s]; lv[s] = lv[s - 1]; lv[s - 1] = tv2;
                        int ti2 = li[s]; li[s] = li[s - 1]; li[s - 1] = ti2;
                    }
                }
            }
        }
    }
#pragma unroll
    for (int p = 0; p < 4; p++) {
        float bv = lv[0]; int bi = li[0];
#pragma unroll
        for (int off = 32; off; off >>= 1) {
            float ov = __shfl_xor(bv, off, 64);
            int oi = __shfl_xor(bi, off, 64);
            if (ov > bv || (ov == bv && oi < bi)) { bv = ov; bi = oi; }
        }
        if (li[0] == bi) {
            lv[0] = lv[1]; li[0] = li[1];
            lv[1] = lv[2]; li[1] = li[2];
            lv[2] = lv[3]; li[2] = li[3];
            lv[3] = -INFINITY; li[3] = 0x7fffffff;
        }
        if (lane == 0) { bt_v[q * 4 + p] = bv; bt_i[q * 4 + p] = bi; }
    }
    __syncthreads();
    if (tid == 0) {
        float fv[16]; int fi[16]; bool used[16];
#pragma unroll
        for (int r = 0; r < 4; r++)
#pragma unroll
            for (int p = 0; p < 4; p++) {
                fv[r * 4 + p] = s_old[r] - LSE[r] + bt_v[r * 4 + p];
                fi[r * 4 + p] = r * VOC + bt_i[r * 4 + p];
                used[r * 4 + p] = false;
            }
        for (int kk = 0; kk < 4; kk++) {
            int best = -1;
            for (int c2 = 0; c2 < 16; c2++) {
                if (used[c2]) continue;
                if (best < 0 || fv[c2] > fv[best] || (fv[c2] == fv[best] && fi[c2] < fi[best])) best = c2;
            }
            used[best] = true;
            int beam = fi[best] / VOC;
            int tok = fi[best] - beam * VOC;
            scores[b * 4 + kk] = fv[best];
            tokens[b * 4 + kk] = tok;
            beamh[(t * BB + b) * 4 + kk] = beam;
            tokh[(t * BB + b) * 4 + kk] = tok;
        }
    }
}

__global__ __launch_bounds__(256) void decode_mega(
    const float* emb, const float* pos,
    const float* Wdq, const float* Wdo, const float* Wd1, const float* Wd2, const float* Wvoc,
    const float* Kmem, const float* Vmem, const float* mb,
    int* tokens, float* scores, int* beamh, int* tokh,
    float* x, float* qdp, float* cctxT, float* cprojp,
    float* hd1, float* hd1T, float* dff1p, float* dff2p,
    float* hd2, float* hd2T,
    float* cmax, float* csum, float* ctv, int* cti,
    int* bar, float* out) {
    __shared__ float smem[6208];     // 24.25 KB (>= 192*32 staging)
    int blk = blockIdx.x;
    int tid = threadIdx.x;
    int gen = 0;

    for (int t = 0; t < TT; t++) {
        // S1: qd = (emb[tok]+pos[t]) @ Wdq (gather-fused); blocks 48..79 write x
        if (blk < 48)
            dev_skinny<96, 1, 0, 0, 1>(smem, nullptr, Wdq, qdp, DMODEL, 0,
                                       blk % 6, blk / 6, tokens, emb, pos, t);
        else if (blk < 80)
            dev_xwrite(blk - 48, tokens, emb, pos, t, x);
        grid_bar(bar, gen);
        // S2: cross-attention
        if (blk < 96) dev_attn(smem, blk, qdp, Kmem, Vmem, mb, cctxT);
        grid_bar(bar, gen);
        // S3: cproj = ctx @ Wdo
        if (blk < 48)
            dev_skinny<96, 1, 0, 0, 0>(smem, cctxT, Wdo, cprojp, DMODEL, 0,
                                       blk % 6, blk / 6, nullptr, nullptr, nullptr, 0);
        grid_bar(bar, gen);
        // S4: hd1 = LN(x + cproj)
        if (blk < 32) dev_lnres<8>(smem, blk, x, cprojp, hd1, hd1T);
        grid_bar(bar, gen);
        // S5: dff1 = hd1 @ Wd1 (partial planes, pre-gelu)
        if (blk < 96)
            dev_skinny<192, 1, 0, 1, 0>(smem, hd1T, Wd1, dff1p, DFF, 0,
                                        blk % 24, blk / 24, nullptr, nullptr, nullptr, 0);
        grid_bar(bar, gen);
        // S6: dff2 = gelu(sum dff1 planes) @ Wd2
        if (blk < 48)
            dev_skinny<384, 4, 1, 0, 0>(smem, dff1p, Wd2, dff2p, DMODEL, DFF * 8,
                                        blk % 6, blk / 6, nullptr, nullptr, nullptr, 0);
        grid_bar(bar, gen);
        // S7: hd2 = LN(hd1 + dff2)
        if (blk < 32) dev_lnres<8>(smem, blk, hd1, dff2p, hd2, hd2T);
        grid_bar(bar, gen);
        // S8: logits chunks + stats
        if (blk < CHN) dev_logits(smem, blk, hd2T, Wvoc, cmax, csum, ctv, cti);
        grid_bar(bar, gen);
        // S9: merge + beam update
        if (blk < BB) dev_merge(smem, blk, cmax, csum, ctv, cti,
                                scores, tokens, beamh, tokh, t);
        grid_bar(bar, gen);
    }

    // backtrack
    if (blk == 0 && tid < 32) {
        int b = tid >> 2, k = tid & 3;
        int ptr = k;
        for (int t = TT - 1; t >= 0; t--) {
            int tok = tokh[(t * BB + b) * KW + ptr];
            out[(size_t)tid * TT + t] = (float)tok;
            ptr = beamh[(t * BB + b) * KW + ptr];
        }
        out[BB * KW * TT + tid] = scores[tid];
    }
}

// ============================ HOST ============================

extern "C" void kernel_launch(void* const* d_in, const int* in_sizes, int n_in,
                              void* d_out, int out_size, void* d_ws, size_t ws_size,
                              hipStream_t stream) {
    const int* X = (const int*)d_in[0];
    const float* emb = (const float*)d_in[1];
    const float* pos = (const float*)d_in[2];
    const float* Wq = (const float*)d_in[3];
    const float* Wk = (const float*)d_in[4];
    const float* Wv = (const float*)d_in[5];
    const float* Wo = (const float*)d_in[6];
    const float* W1 = (const float*)d_in[7];
    const float* W2 = (const float*)d_in[8];
    const float* Wdq = (const float*)d_in[9];
    const float* Wdk = (const float*)d_in[10];
    const float* Wdv = (const float*)d_in[11];
    const float* Wdo = (const float*)d_in[12];
    const float* Wd1 = (const float*)d_in[13];
    const float* Wd2 = (const float*)d_in[14];
    const float* Wvoc = (const float*)d_in[15];

    float* ws = (float*)d_ws;
    size_t o = 0;
    auto alloc = [&](size_t n) { float* p = ws + o; o += n; return p; };

    const size_t ROWS = (size_t)BB * SS;       // 1024
    const size_t HD = ROWS * DMODEL;

    // persistent
    float* mb = alloc(ROWS);
    float* Kmem = alloc(HD);
    float* Vmem = alloc(HD);
    float* scores = alloc(32);
    int* tokens = (int*)alloc(32);
    int* beamh = (int*)alloc(TT * BB * KW);
    int* tokh = (int*)alloc(TT * BB * KW);
    int* bar = (int*)alloc(8);

    size_t mark = o;
    // encoder scratch
    float* h0 = alloc(HD);
    float* qb = alloc(HD);
    float* kb = alloc(HD);
    float* vb = alloc(HD);
    float* attc = alloc(HD);
    float* attp = alloc(HD);
    float* h1 = alloc(HD);
    float* ff1 = alloc(ROWS * DFF);
    float* ff2 = alloc(HD);
    float* memb = alloc(HD);

    // decoder scratch (aliases encoder scratch)
    o = mark;
    float* x = alloc(P32);
    float* qdp = alloc(8 * P32);
    float* cctxT = alloc(P32);
    float* cprojp = alloc(8 * P32);
    float* hd1 = alloc(P32);
    float* hd1T = alloc(P32);
    float* dff1p = alloc((size_t)4 * DFF * 32);
    float* dff2p = alloc(8 * P32);
    float* hd2 = alloc(P32);
    float* hd2T = alloc(P32);
    float* cmax = alloc(32 * CHN);
    float* csum = alloc(32 * CHN);
    float* ctv = alloc((size_t)32 * CHN * 4);
    int* cti = (int*)alloc((size_t)32 * CHN * 4);
    float* outp = (float*)d_out;
    (void)ws_size; (void)in_sizes; (void)n_in; (void)out_size;

    init_k<<<1, 64, 0, stream>>>(tokens, scores, bar);

    // ---- encoder ----
    embed_enc<<<dim3(ROWS), 256, 0, stream>>>(X, emb, pos, h0, mb);
    dim3 g768(DMODEL / 64, ROWS / 64);
    dim3 g3072(DFF / 64, ROWS / 64);
    gemm64<DMODEL, 0><<<g768, 256, 0, stream>>>(h0, Wq, qb, DMODEL);
    gemm64<DMODEL, 0><<<g768, 256, 0, stream>>>(h0, Wk, kb, DMODEL);
    gemm64<DMODEL, 0><<<g768, 256, 0, stream>>>(h0, Wv, vb, DMODEL);
    enc_attn<<<dim3(BB * HN * SS), 64, 0, stream>>>(qb, kb, vb, mb, attc);
    gemm64<DMODEL, 0><<<g768, 256, 0, stream>>>(attc, Wo, attp, DMODEL);
    lnres_enc<<<dim3(ROWS), 256, 0, stream>>>(h0, attp, h1);
    gemm64<DMODEL, 1><<<g3072, 256, 0, stream>>>(h1, W1, ff1, DFF);
    gemm64<DFF, 0><<<g768, 256, 0, stream>>>(ff1, W2, ff2, DMODEL);
    lnres_enc<<<dim3(ROWS), 256, 0, stream>>>(h1, ff2, memb);
    gemm64<DMODEL, 0><<<g768, 256, 0, stream>>>(memb, Wdk, Kmem, DMODEL);
    gemm64<DMODEL, 0><<<g768, 256, 0, stream>>>(memb, Wdv, Vmem, DMODEL);

    // ---- beam search decode: persistent megakernel, manual grid barrier ----
    decode_mega<<<dim3(NBLK), 256, 0, stream>>>(
        emb, pos, Wdq, Wdo, Wd1, Wd2, Wvoc,
        Kmem, Vmem, mb,
        tokens, scores, beamh, tokh,
        x, qdp, cctxT, cprojp,
        hd1, hd1T, dff1p, dff2p,
        hd2, hd2T,
        cmax, csum, ctv, cti,
        bar, outp);
}